// Round 3
// baseline (1889.695 us; speedup 1.0000x reference)
//
#include <hip/hip_runtime.h>
#include <math.h>

#define NN 100000
#define NE 1600000
#define NGR 1000

// ---------------- CSR build ----------------
__global__ void k_count(const int* __restrict__ dst, int* __restrict__ deg) {
    int e = blockIdx.x * 256 + threadIdx.x;
    if (e < NE) atomicAdd(&deg[dst[e]], 1);
}

__global__ void k_blocksum(const int* __restrict__ deg, int* __restrict__ bsum) {
    __shared__ int sdata[4];
    int t = threadIdx.x;
    int base = blockIdx.x * 1024 + t * 4;
    int s = 0;
    #pragma unroll
    for (int k = 0; k < 4; k++) { int i = base + k; if (i < NN) s += deg[i]; }
    for (int o = 32; o; o >>= 1) s += __shfl_xor(s, o);
    if ((t & 63) == 0) sdata[t >> 6] = s;
    __syncthreads();
    if (t == 0) bsum[blockIdx.x] = sdata[0] + sdata[1] + sdata[2] + sdata[3];
}

__global__ void k_scanbsum(int* __restrict__ bsum, int nb, int* __restrict__ row_start) {
    if (threadIdx.x == 0 && blockIdx.x == 0) {
        int acc = 0;
        for (int i = 0; i < nb; i++) { int v = bsum[i]; bsum[i] = acc; acc += v; }
        row_start[NN] = acc;
    }
}

__global__ void k_scanblocks(const int* __restrict__ deg, const int* __restrict__ bsum,
                             int* __restrict__ row_start) {
    __shared__ int wsum[4];
    int t = threadIdx.x, lane = t & 63, w = t >> 6;
    int base = blockIdx.x * 1024 + t * 4;
    int a0 = (base     < NN) ? deg[base]     : 0;
    int a1 = (base + 1 < NN) ? deg[base + 1] : 0;
    int a2 = (base + 2 < NN) ? deg[base + 2] : 0;
    int a3 = (base + 3 < NN) ? deg[base + 3] : 0;
    int ts = a0 + a1 + a2 + a3;
    int incl = ts;
    for (int d = 1; d < 64; d <<= 1) { int v = __shfl_up(incl, d); if (lane >= d) incl += v; }
    if (lane == 63) wsum[w] = incl;
    __syncthreads();
    int woff = bsum[blockIdx.x];
    for (int i = 0; i < w; i++) woff += wsum[i];
    int excl = woff + incl - ts;
    if (base     < NN) row_start[base]     = excl;
    if (base + 1 < NN) row_start[base + 1] = excl + a0;
    if (base + 2 < NN) row_start[base + 2] = excl + a0 + a1;
    if (base + 3 < NN) row_start[base + 3] = excl + a0 + a1 + a2;
}

__global__ void k_fill(const int* __restrict__ src, const int* __restrict__ dst,
                       const int* __restrict__ row_start, int* __restrict__ cursor,
                       int* __restrict__ csr_src) {
    int e = blockIdx.x * 256 + threadIdx.x;
    if (e < NE) {
        int d = dst[e];
        int p = atomicAdd(&cursor[d], 1);
        csr_src[row_start[d] + p] = src[e];
    }
}

// ---------------- layer pass 1: agg + combine + GEMM1 + BN1 stats ----------------
template <bool DONORM>
__global__ __launch_bounds__(256, 4) void k_pass1(
    const float* __restrict__ hsrc,
    const float* __restrict__ pstats, const float* __restrict__ pg, const float* __restrict__ pbe,
    const int* __restrict__ row_start, const int* __restrict__ csr_src,
    const float* __restrict__ epsp, int layer,
    const float* __restrict__ W, const float* __restrict__ bb,
    float* __restrict__ uout, float* __restrict__ stats)
{
    __shared__ float zbuf[128 * 64];
    int t = threadIdx.x, lane = t & 63, w = t >> 6;
    int rowbase = blockIdx.x * 128 + w * 32;
    float an = 1.f, cn = 0.f;
    if (DONORM) {
        float mu  = pstats[lane] * (1.0f / NN);
        float var = pstats[64 + lane] * (1.0f / NN) - mu * mu;
        float inv = rsqrtf(var + 1e-5f);
        an = pg[lane] * inv;
        cn = pbe[lane] - mu * an;
    }
    float epsl = 1.0f + epsp[layer];
    float* zw = &zbuf[w * 32 * 64];

    for (int r = 0; r < 32; r++) {
        int i = rowbase + r;
        float zf = 0.f;
        if (i < NN) {
            float hv = hsrc[i * 64 + lane];
            if (DONORM) hv = fmaxf(fmaf(an, hv, cn), 0.f);
            zf = epsl * hv;
            int e0 = row_start[i], e1 = row_start[i + 1];
            for (int e = e0; e < e1; e++) {
                int s = csr_src[e];
                float hv2 = hsrc[s * 64 + lane];
                if (DONORM) hv2 = fmaxf(fmaf(an, hv2, cn), 0.f);
                zf += hv2;
            }
        }
        zw[r * 64 + lane] = zf;
    }

    float wc[64];
    #pragma unroll
    for (int k = 0; k < 64; k++) wc[k] = W[k * 64 + lane];
    float bj = bb[lane];
    float s1 = 0.f, s2 = 0.f;
    for (int r = 0; r < 32; r++) {
        int i = rowbase + r;
        if (i >= NN) break;
        float acc = bj;
        const float4* zr = (const float4*)&zw[r * 64];
        #pragma unroll
        for (int k4 = 0; k4 < 16; k4++) {
            float4 zv = zr[k4];
            acc = fmaf(zv.x, wc[4 * k4 + 0], acc);
            acc = fmaf(zv.y, wc[4 * k4 + 1], acc);
            acc = fmaf(zv.z, wc[4 * k4 + 2], acc);
            acc = fmaf(zv.w, wc[4 * k4 + 3], acc);
        }
        uout[i * 64 + lane] = acc;
        s1 += acc; s2 += acc * acc;
    }
    atomicAdd(&stats[lane], s1);
    atomicAdd(&stats[64 + lane], s2);
}

// ---------------- layer pass 2: BN1 apply + relu + GEMM2 + BN2 stats ----------------
__global__ __launch_bounds__(256, 4) void k_pass2(
    const float* __restrict__ uin,
    const float* __restrict__ st1, const float* __restrict__ gg, const float* __restrict__ bee,
    const float* __restrict__ W, const float* __restrict__ bb,
    float* __restrict__ wout, float* __restrict__ stats)
{
    __shared__ float zbuf[128 * 64];
    int t = threadIdx.x, lane = t & 63, w = t >> 6;
    int rowbase = blockIdx.x * 128 + w * 32;
    float mu  = st1[lane] * (1.0f / NN);
    float var = st1[64 + lane] * (1.0f / NN) - mu * mu;
    float inv = rsqrtf(var + 1e-5f);
    float a = gg[lane] * inv;
    float c = bee[lane] - mu * a;
    float* zw = &zbuf[w * 32 * 64];

    for (int r = 0; r < 32; r++) {
        int i = rowbase + r;
        float zf = 0.f;
        if (i < NN) zf = fmaxf(fmaf(a, uin[i * 64 + lane], c), 0.f);
        zw[r * 64 + lane] = zf;
    }

    float wc[64];
    #pragma unroll
    for (int k = 0; k < 64; k++) wc[k] = W[k * 64 + lane];
    float bj = bb[lane];
    float s1 = 0.f, s2 = 0.f;
    for (int r = 0; r < 32; r++) {
        int i = rowbase + r;
        if (i >= NN) break;
        float acc = bj;
        const float4* zr = (const float4*)&zw[r * 64];
        #pragma unroll
        for (int k4 = 0; k4 < 16; k4++) {
            float4 zv = zr[k4];
            acc = fmaf(zv.x, wc[4 * k4 + 0], acc);
            acc = fmaf(zv.y, wc[4 * k4 + 1], acc);
            acc = fmaf(zv.z, wc[4 * k4 + 2], acc);
            acc = fmaf(zv.w, wc[4 * k4 + 3], acc);
        }
        wout[i * 64 + lane] = acc;
        s1 += acc; s2 += acc * acc;
    }
    atomicAdd(&stats[lane], s1);
    atomicAdd(&stats[64 + lane], s2);
}

// ---------------- final: BN2 apply ×3 + concat-GEMM (K=192) + bias + relu + gate ----------------
__global__ __launch_bounds__(256, 3) void k_final(
    const float* __restrict__ w0, const float* __restrict__ w1, const float* __restrict__ w2,
    const float* __restrict__ stats, const float* __restrict__ g2, const float* __restrict__ be2,
    const float* __restrict__ lin1W, const float* __restrict__ lin1b,
    const float* __restrict__ gateW, const float* __restrict__ gateB,
    float* __restrict__ hh, float* __restrict__ gate)
{
    __shared__ float zbuf[128 * 64];
    int t = threadIdx.x, lane = t & 63, w = t >> 6;
    int rowbase = blockIdx.x * 128 + w * 32;
    float* zw = &zbuf[w * 32 * 64];

    float acc[32];
    #pragma unroll
    for (int r = 0; r < 32; r++) acc[r] = 0.f;

    for (int l = 0; l < 3; l++) {
        const float* wl = (l == 0) ? w0 : ((l == 1) ? w1 : w2);
        const float* st = stats + (l * 2 + 1) * 128;
        float mu  = st[lane] * (1.0f / NN);
        float var = st[64 + lane] * (1.0f / NN) - mu * mu;
        float inv = rsqrtf(var + 1e-5f);
        float a = g2[l * 64 + lane] * inv;
        float c = be2[l * 64 + lane] - mu * a;

        for (int r = 0; r < 32; r++) {
            int i = rowbase + r;
            float zf = 0.f;
            if (i < NN) zf = fmaxf(fmaf(a, wl[i * 64 + lane], c), 0.f);
            zw[r * 64 + lane] = zf;
        }

        float wc[64];
        #pragma unroll
        for (int k = 0; k < 64; k++) wc[k] = lin1W[(l * 64 + k) * 64 + lane];

        #pragma unroll
        for (int r = 0; r < 32; r++) {
            const float4* zr = (const float4*)&zw[r * 64];
            float a2 = acc[r];
            #pragma unroll
            for (int k4 = 0; k4 < 16; k4++) {
                float4 zv = zr[k4];
                a2 = fmaf(zv.x, wc[4 * k4 + 0], a2);
                a2 = fmaf(zv.y, wc[4 * k4 + 1], a2);
                a2 = fmaf(zv.z, wc[4 * k4 + 2], a2);
                a2 = fmaf(zv.w, wc[4 * k4 + 3], a2);
            }
            acc[r] = a2;
        }
    }

    float gw = gateW[lane];
    float gb = gateB[0];
    float lb = lin1b[lane];
    #pragma unroll
    for (int r = 0; r < 32; r++) {
        int i = rowbase + r;
        if (i < NN) {
            float h = fmaxf(acc[r] + lb, 0.f);
            hh[i * 64 + lane] = h;
            float gg = h * gw;
            for (int o = 32; o; o >>= 1) gg += __shfl_xor(gg, o);
            if (lane == 0) gate[i] = gg + gb;
        }
    }
}

// ---------------- graph boundaries + attentional pooling ----------------
__global__ void k_bounds(const int* __restrict__ batch_idx, int* __restrict__ gstart) {
    int g = blockIdx.x * 256 + threadIdx.x;
    if (g <= NGR) {
        int lo = 0, hi = NN;
        while (lo < hi) { int mid = (lo + hi) >> 1; if (batch_idx[mid] < g) lo = mid + 1; else hi = mid; }
        gstart[g] = lo;
    }
}

__global__ __launch_bounds__(256) void k_pool(const float* __restrict__ hh, const float* __restrict__ gate,
                                              const int* __restrict__ gstart, float* __restrict__ pooled) {
    __shared__ float red[4];
    __shared__ float pbuf[256];
    __shared__ float m_sh, d_sh;
    int g = blockIdx.x;
    int s = gstart[g], e = gstart[g + 1];
    int t = threadIdx.x, lane = t & 63, w = t >> 6;

    float m = -INFINITY;
    for (int i = s + t; i < e; i += 256) m = fmaxf(m, gate[i]);
    for (int o = 32; o; o >>= 1) m = fmaxf(m, __shfl_xor(m, o));
    if (lane == 0) red[w] = m;
    __syncthreads();
    if (t == 0) m_sh = fmaxf(fmaxf(red[0], red[1]), fmaxf(red[2], red[3]));
    __syncthreads();
    m = m_sh;

    float sum = 0.f;
    for (int i = s + t; i < e; i += 256) sum += expf(gate[i] - m);
    for (int o = 32; o; o >>= 1) sum += __shfl_xor(sum, o);
    if (lane == 0) red[w] = sum;
    __syncthreads();
    if (t == 0) d_sh = red[0] + red[1] + red[2] + red[3];
    __syncthreads();
    float denom = d_sh;

    float acc = 0.f;
    for (int i = s + w; i < e; i += 4) acc += expf(gate[i] - m) * hh[i * 64 + lane];
    pbuf[w * 64 + lane] = acc;
    __syncthreads();
    if (t < 64) {
        float tot = pbuf[t] + pbuf[64 + t] + pbuf[128 + t] + pbuf[192 + t];
        pooled[g * 64 + t] = (e > s) ? tot / denom : 0.f;
    }
}

// ---------------- launcher ----------------
extern "C" void kernel_launch(void* const* d_in, const int* in_sizes, int n_in,
                              void* d_out, int out_size, void* d_ws, size_t ws_size,
                              hipStream_t stream) {
    (void)in_sizes; (void)n_in; (void)out_size; (void)ws_size;
    const float* x     = (const float*)d_in[0];
    const int*   ei    = (const int*)d_in[1];
    const int*   src   = ei;
    const int*   dst   = ei + NE;
    const int*   bidx  = (const int*)d_in[2];
    const float* epsp  = (const float*)d_in[3];
    const float* W1    = (const float*)d_in[4];
    const float* b1    = (const float*)d_in[5];
    const float* g1    = (const float*)d_in[6];
    const float* be1   = (const float*)d_in[7];
    const float* W2    = (const float*)d_in[8];
    const float* b2    = (const float*)d_in[9];
    const float* g2    = (const float*)d_in[10];
    const float* be2   = (const float*)d_in[11];
    const float* lin1W = (const float*)d_in[12];
    const float* lin1b = (const float*)d_in[13];
    const float* gateW = (const float*)d_in[14];
    const float* gateB = (const float*)d_in[15];

    int* deg       = (int*)d_ws;
    int* cursor    = deg + NN;
    float* stats   = (float*)(cursor + NN);      // 12*64 = 768 floats
    int* row_start = (int*)(stats + 768);        // NN+1
    int* csr_src   = row_start + NN + 1;         // NE
    int* bsum      = csr_src + NE;               // 128
    float* u       = (float*)(bsum + 128);       // NN*64
    float* w0      = u   + (size_t)NN * 64;
    float* w1v     = w0  + (size_t)NN * 64;
    float* w2v     = w1v + (size_t)NN * 64;
    float* gate    = w2v + (size_t)NN * 64;      // NN
    int* gstart    = (int*)(gate + NN);          // NGR+1

    float* hh     = (float*)d_out;
    float* pooled = hh + (size_t)NN * 64;

    hipMemsetAsync(d_ws, 0, (size_t)(2 * NN + 768) * 4, stream);

    k_count<<<(NE + 255) / 256, 256, 0, stream>>>(dst, deg);
    int nb = (NN + 1023) / 1024;
    k_blocksum<<<nb, 256, 0, stream>>>(deg, bsum);
    k_scanbsum<<<1, 64, 0, stream>>>(bsum, nb, row_start);
    k_scanblocks<<<nb, 256, 0, stream>>>(deg, bsum, row_start);
    k_fill<<<(NE + 255) / 256, 256, 0, stream>>>(src, dst, row_start, cursor, csr_src);

    int nblk = (NN + 127) / 128;
    // layer 0
    k_pass1<false><<<nblk, 256, 0, stream>>>(x, nullptr, nullptr, nullptr, row_start, csr_src,
                                             epsp, 0, W1, b1, u, stats + 0);
    k_pass2<<<nblk, 256, 0, stream>>>(u, stats + 0, g1, be1, W2, b2, w0, stats + 128);
    // layer 1
    k_pass1<true><<<nblk, 256, 0, stream>>>(w0, stats + 128, g2, be2, row_start, csr_src,
                                            epsp, 1, W1 + 4096, b1 + 64, u, stats + 256);
    k_pass2<<<nblk, 256, 0, stream>>>(u, stats + 256, g1 + 64, be1 + 64, W2 + 4096, b2 + 64, w1v, stats + 384);
    // layer 2
    k_pass1<true><<<nblk, 256, 0, stream>>>(w1v, stats + 384, g2 + 64, be2 + 64, row_start, csr_src,
                                            epsp, 2, W1 + 8192, b1 + 128, u, stats + 512);
    k_pass2<<<nblk, 256, 0, stream>>>(u, stats + 512, g1 + 128, be1 + 128, W2 + 8192, b2 + 128, w2v, stats + 640);

    k_final<<<nblk, 256, 0, stream>>>(w0, w1v, w2v, stats, g2, be2, lin1W, lin1b, gateW, gateB, hh, gate);
    k_bounds<<<(NGR + 256) / 256, 256, 0, stream>>>(bidx, gstart);
    k_pool<<<NGR, 256, 0, stream>>>(hh, gate, gstart, pooled);
}

// Round 4
// 1630.730 us; speedup vs baseline: 1.1588x; 1.1588x over previous
//
#include <hip/hip_runtime.h>
#include <math.h>

#define NN 100000
#define NE 1600000
#define NGR 1000

// ---------------- CSR build ----------------
__global__ void k_count(const int* __restrict__ dst, int* __restrict__ deg) {
    int e = blockIdx.x * 256 + threadIdx.x;
    if (e < NE) atomicAdd(&deg[dst[e]], 1);
}

__global__ void k_blocksum(const int* __restrict__ deg, int* __restrict__ bsum) {
    __shared__ int sdata[4];
    int t = threadIdx.x;
    int base = blockIdx.x * 1024 + t * 4;
    int s = 0;
    #pragma unroll
    for (int k = 0; k < 4; k++) { int i = base + k; if (i < NN) s += deg[i]; }
    for (int o = 32; o; o >>= 1) s += __shfl_xor(s, o);
    if ((t & 63) == 0) sdata[t >> 6] = s;
    __syncthreads();
    if (t == 0) bsum[blockIdx.x] = sdata[0] + sdata[1] + sdata[2] + sdata[3];
}

__global__ void k_scanbsum(int* __restrict__ bsum, int nb, int* __restrict__ row_start) {
    if (threadIdx.x == 0 && blockIdx.x == 0) {
        int acc = 0;
        for (int i = 0; i < nb; i++) { int v = bsum[i]; bsum[i] = acc; acc += v; }
        row_start[NN] = acc;
    }
}

__global__ void k_scanblocks(const int* __restrict__ deg, const int* __restrict__ bsum,
                             int* __restrict__ row_start) {
    __shared__ int wsum[4];
    int t = threadIdx.x, lane = t & 63, w = t >> 6;
    int base = blockIdx.x * 1024 + t * 4;
    int a0 = (base     < NN) ? deg[base]     : 0;
    int a1 = (base + 1 < NN) ? deg[base + 1] : 0;
    int a2 = (base + 2 < NN) ? deg[base + 2] : 0;
    int a3 = (base + 3 < NN) ? deg[base + 3] : 0;
    int ts = a0 + a1 + a2 + a3;
    int incl = ts;
    for (int d = 1; d < 64; d <<= 1) { int v = __shfl_up(incl, d); if (lane >= d) incl += v; }
    if (lane == 63) wsum[w] = incl;
    __syncthreads();
    int woff = bsum[blockIdx.x];
    for (int i = 0; i < w; i++) woff += wsum[i];
    int excl = woff + incl - ts;
    if (base     < NN) row_start[base]     = excl;
    if (base + 1 < NN) row_start[base + 1] = excl + a0;
    if (base + 2 < NN) row_start[base + 2] = excl + a0 + a1;
    if (base + 3 < NN) row_start[base + 3] = excl + a0 + a1 + a2;
}

__global__ void k_fill(const int* __restrict__ src, const int* __restrict__ dst,
                       const int* __restrict__ row_start, int* __restrict__ cursor,
                       int* __restrict__ csr_src) {
    int e = blockIdx.x * 256 + threadIdx.x;
    if (e < NE) {
        int d = dst[e];
        int p = atomicAdd(&cursor[d], 1);
        csr_src[row_start[d] + p] = src[e];
    }
}

// ---------------- layer pass 1: agg + combine + GEMM1 + BN1 stats ----------------
// 16 rows per wave, 64 rows per block; 4-way MLP in the gather loop.
template <bool DONORM>
__global__ __launch_bounds__(256, 6) void k_pass1(
    const float* __restrict__ hsrc,
    const float* __restrict__ pstats, const float* __restrict__ pg, const float* __restrict__ pbe,
    const int* __restrict__ row_start, const int* __restrict__ csr_src,
    const float* __restrict__ epsp, int layer,
    const float* __restrict__ W, const float* __restrict__ bb,
    float* __restrict__ uout, float* __restrict__ stats)
{
    __shared__ float zbuf[64 * 64];
    int t = threadIdx.x, lane = t & 63, w = t >> 6;
    int rowbase = blockIdx.x * 64 + w * 16;
    float an = 1.f, cn = 0.f;
    if (DONORM) {
        float mu  = pstats[lane] * (1.0f / NN);
        float var = pstats[64 + lane] * (1.0f / NN) - mu * mu;
        float inv = rsqrtf(var + 1e-5f);
        an = pg[lane] * inv;
        cn = pbe[lane] - mu * an;
    }
    float epsl = 1.0f + epsp[layer];
    float* zw = &zbuf[w * 16 * 64];

    for (int r = 0; r < 16; r++) {
        int i = rowbase + r;
        float zf = 0.f;
        if (i < NN) {
            float hv = hsrc[i * 64 + lane];
            if (DONORM) hv = fmaxf(fmaf(an, hv, cn), 0.f);
            zf = epsl * hv;
            int e0 = row_start[i], e1 = row_start[i + 1];
            float a0 = 0.f, a1 = 0.f, a2 = 0.f, a3 = 0.f;
            int e = e0;
            for (; e + 4 <= e1; e += 4) {
                int s0 = csr_src[e + 0];
                int s1 = csr_src[e + 1];
                int s2 = csr_src[e + 2];
                int s3 = csr_src[e + 3];
                float v0 = hsrc[s0 * 64 + lane];
                float v1 = hsrc[s1 * 64 + lane];
                float v2 = hsrc[s2 * 64 + lane];
                float v3 = hsrc[s3 * 64 + lane];
                if (DONORM) {
                    v0 = fmaxf(fmaf(an, v0, cn), 0.f);
                    v1 = fmaxf(fmaf(an, v1, cn), 0.f);
                    v2 = fmaxf(fmaf(an, v2, cn), 0.f);
                    v3 = fmaxf(fmaf(an, v3, cn), 0.f);
                }
                a0 += v0; a1 += v1; a2 += v2; a3 += v3;
            }
            for (; e < e1; e++) {
                int s = csr_src[e];
                float v = hsrc[s * 64 + lane];
                if (DONORM) v = fmaxf(fmaf(an, v, cn), 0.f);
                a0 += v;
            }
            zf += (a0 + a1) + (a2 + a3);
        }
        zw[r * 64 + lane] = zf;
    }

    float wc[64];
    #pragma unroll
    for (int k = 0; k < 64; k++) wc[k] = W[k * 64 + lane];
    float bj = bb[lane];
    float s1 = 0.f, s2 = 0.f;
    for (int r = 0; r < 16; r++) {
        int i = rowbase + r;
        if (i >= NN) break;
        float acc = bj;
        const float4* zr = (const float4*)&zw[r * 64];
        #pragma unroll
        for (int k4 = 0; k4 < 16; k4++) {
            float4 zv = zr[k4];
            acc = fmaf(zv.x, wc[4 * k4 + 0], acc);
            acc = fmaf(zv.y, wc[4 * k4 + 1], acc);
            acc = fmaf(zv.z, wc[4 * k4 + 2], acc);
            acc = fmaf(zv.w, wc[4 * k4 + 3], acc);
        }
        uout[i * 64 + lane] = acc;
        s1 += acc; s2 += acc * acc;
    }
    atomicAdd(&stats[lane], s1);
    atomicAdd(&stats[64 + lane], s2);
}

// ---------------- layer pass 2: BN1 apply + relu + GEMM2 + BN2 stats ----------------
__global__ __launch_bounds__(256, 4) void k_pass2(
    const float* __restrict__ uin,
    const float* __restrict__ st1, const float* __restrict__ gg, const float* __restrict__ bee,
    const float* __restrict__ W, const float* __restrict__ bb,
    float* __restrict__ wout, float* __restrict__ stats)
{
    __shared__ float zbuf[128 * 64];
    int t = threadIdx.x, lane = t & 63, w = t >> 6;
    int rowbase = blockIdx.x * 128 + w * 32;
    float mu  = st1[lane] * (1.0f / NN);
    float var = st1[64 + lane] * (1.0f / NN) - mu * mu;
    float inv = rsqrtf(var + 1e-5f);
    float a = gg[lane] * inv;
    float c = bee[lane] - mu * a;
    float* zw = &zbuf[w * 32 * 64];

    for (int r = 0; r < 32; r++) {
        int i = rowbase + r;
        float zf = 0.f;
        if (i < NN) zf = fmaxf(fmaf(a, uin[i * 64 + lane], c), 0.f);
        zw[r * 64 + lane] = zf;
    }

    float wc[64];
    #pragma unroll
    for (int k = 0; k < 64; k++) wc[k] = W[k * 64 + lane];
    float bj = bb[lane];
    float s1 = 0.f, s2 = 0.f;
    for (int r = 0; r < 32; r++) {
        int i = rowbase + r;
        if (i >= NN) break;
        float acc = bj;
        const float4* zr = (const float4*)&zw[r * 64];
        #pragma unroll
        for (int k4 = 0; k4 < 16; k4++) {
            float4 zv = zr[k4];
            acc = fmaf(zv.x, wc[4 * k4 + 0], acc);
            acc = fmaf(zv.y, wc[4 * k4 + 1], acc);
            acc = fmaf(zv.z, wc[4 * k4 + 2], acc);
            acc = fmaf(zv.w, wc[4 * k4 + 3], acc);
        }
        wout[i * 64 + lane] = acc;
        s1 += acc; s2 += acc * acc;
    }
    atomicAdd(&stats[lane], s1);
    atomicAdd(&stats[64 + lane], s2);
}

// ---------------- final: BN2 apply ×3 + concat-GEMM (K=192) + bias + relu + gate ----------------
__global__ __launch_bounds__(256, 3) void k_final(
    const float* __restrict__ w0, const float* __restrict__ w1, const float* __restrict__ w2,
    const float* __restrict__ stats, const float* __restrict__ g2, const float* __restrict__ be2,
    const float* __restrict__ lin1W, const float* __restrict__ lin1b,
    const float* __restrict__ gateW, const float* __restrict__ gateB,
    float* __restrict__ hh, float* __restrict__ gate)
{
    __shared__ float zbuf[128 * 64];
    int t = threadIdx.x, lane = t & 63, w = t >> 6;
    int rowbase = blockIdx.x * 128 + w * 32;
    float* zw = &zbuf[w * 32 * 64];

    float acc[32];
    #pragma unroll
    for (int r = 0; r < 32; r++) acc[r] = 0.f;

    for (int l = 0; l < 3; l++) {
        const float* wl = (l == 0) ? w0 : ((l == 1) ? w1 : w2);
        const float* st = stats + (l * 2 + 1) * 128;
        float mu  = st[lane] * (1.0f / NN);
        float var = st[64 + lane] * (1.0f / NN) - mu * mu;
        float inv = rsqrtf(var + 1e-5f);
        float a = g2[l * 64 + lane] * inv;
        float c = be2[l * 64 + lane] - mu * a;

        for (int r = 0; r < 32; r++) {
            int i = rowbase + r;
            float zf = 0.f;
            if (i < NN) zf = fmaxf(fmaf(a, wl[i * 64 + lane], c), 0.f);
            zw[r * 64 + lane] = zf;
        }

        float wc[64];
        #pragma unroll
        for (int k = 0; k < 64; k++) wc[k] = lin1W[(l * 64 + k) * 64 + lane];

        #pragma unroll
        for (int r = 0; r < 32; r++) {
            const float4* zr = (const float4*)&zw[r * 64];
            float a2 = acc[r];
            #pragma unroll
            for (int k4 = 0; k4 < 16; k4++) {
                float4 zv = zr[k4];
                a2 = fmaf(zv.x, wc[4 * k4 + 0], a2);
                a2 = fmaf(zv.y, wc[4 * k4 + 1], a2);
                a2 = fmaf(zv.z, wc[4 * k4 + 2], a2);
                a2 = fmaf(zv.w, wc[4 * k4 + 3], a2);
            }
            acc[r] = a2;
        }
    }

    float gw = gateW[lane];
    float gb = gateB[0];
    float lb = lin1b[lane];
    #pragma unroll
    for (int r = 0; r < 32; r++) {
        int i = rowbase + r;
        if (i < NN) {
            float h = fmaxf(acc[r] + lb, 0.f);
            hh[i * 64 + lane] = h;
            float gg = h * gw;
            for (int o = 32; o; o >>= 1) gg += __shfl_xor(gg, o);
            if (lane == 0) gate[i] = gg + gb;
        }
    }
}

// ---------------- graph boundaries + attentional pooling ----------------
__global__ void k_bounds(const int* __restrict__ batch_idx, int* __restrict__ gstart) {
    int g = blockIdx.x * 256 + threadIdx.x;
    if (g <= NGR) {
        int lo = 0, hi = NN;
        while (lo < hi) { int mid = (lo + hi) >> 1; if (batch_idx[mid] < g) lo = mid + 1; else hi = mid; }
        gstart[g] = lo;
    }
}

__global__ __launch_bounds__(256) void k_pool(const float* __restrict__ hh, const float* __restrict__ gate,
                                              const int* __restrict__ gstart, float* __restrict__ pooled) {
    __shared__ float red[4];
    __shared__ float pbuf[256];
    __shared__ float m_sh, d_sh;
    int g = blockIdx.x;
    int s = gstart[g], e = gstart[g + 1];
    int t = threadIdx.x, lane = t & 63, w = t >> 6;

    float m = -INFINITY;
    for (int i = s + t; i < e; i += 256) m = fmaxf(m, gate[i]);
    for (int o = 32; o; o >>= 1) m = fmaxf(m, __shfl_xor(m, o));
    if (lane == 0) red[w] = m;
    __syncthreads();
    if (t == 0) m_sh = fmaxf(fmaxf(red[0], red[1]), fmaxf(red[2], red[3]));
    __syncthreads();
    m = m_sh;

    float sum = 0.f;
    for (int i = s + t; i < e; i += 256) sum += expf(gate[i] - m);
    for (int o = 32; o; o >>= 1) sum += __shfl_xor(sum, o);
    if (lane == 0) red[w] = sum;
    __syncthreads();
    if (t == 0) d_sh = red[0] + red[1] + red[2] + red[3];
    __syncthreads();
    float denom = d_sh;

    float acc = 0.f;
    for (int i = s + w; i < e; i += 4) acc += expf(gate[i] - m) * hh[i * 64 + lane];
    pbuf[w * 64 + lane] = acc;
    __syncthreads();
    if (t < 64) {
        float tot = pbuf[t] + pbuf[64 + t] + pbuf[128 + t] + pbuf[192 + t];
        pooled[g * 64 + t] = (e > s) ? tot / denom : 0.f;
    }
}

// ---------------- launcher ----------------
extern "C" void kernel_launch(void* const* d_in, const int* in_sizes, int n_in,
                              void* d_out, int out_size, void* d_ws, size_t ws_size,
                              hipStream_t stream) {
    (void)in_sizes; (void)n_in; (void)out_size; (void)ws_size;
    const float* x     = (const float*)d_in[0];
    const int*   ei    = (const int*)d_in[1];
    const int*   src   = ei;
    const int*   dst   = ei + NE;
    const int*   bidx  = (const int*)d_in[2];
    const float* epsp  = (const float*)d_in[3];
    const float* W1    = (const float*)d_in[4];
    const float* b1    = (const float*)d_in[5];
    const float* g1    = (const float*)d_in[6];
    const float* be1   = (const float*)d_in[7];
    const float* W2    = (const float*)d_in[8];
    const float* b2    = (const float*)d_in[9];
    const float* g2    = (const float*)d_in[10];
    const float* be2   = (const float*)d_in[11];
    const float* lin1W = (const float*)d_in[12];
    const float* lin1b = (const float*)d_in[13];
    const float* gateW = (const float*)d_in[14];
    const float* gateB = (const float*)d_in[15];

    int* deg       = (int*)d_ws;
    int* cursor    = deg + NN;
    float* stats   = (float*)(cursor + NN);      // 12*64 = 768 floats
    int* row_start = (int*)(stats + 768);        // NN+1
    int* csr_src   = row_start + NN + 1;         // NE
    int* bsum      = csr_src + NE;               // 128
    float* u       = (float*)(bsum + 128);       // NN*64
    float* w0      = u   + (size_t)NN * 64;
    float* w1v     = w0  + (size_t)NN * 64;
    float* w2v     = w1v + (size_t)NN * 64;
    float* gate    = w2v + (size_t)NN * 64;      // NN
    int* gstart    = (int*)(gate + NN);          // NGR+1

    float* hh     = (float*)d_out;
    float* pooled = hh + (size_t)NN * 64;

    hipMemsetAsync(d_ws, 0, (size_t)(2 * NN + 768) * 4, stream);

    k_count<<<(NE + 255) / 256, 256, 0, stream>>>(dst, deg);
    int nb = (NN + 1023) / 1024;
    k_blocksum<<<nb, 256, 0, stream>>>(deg, bsum);
    k_scanbsum<<<1, 64, 0, stream>>>(bsum, nb, row_start);
    k_scanblocks<<<nb, 256, 0, stream>>>(deg, bsum, row_start);
    k_fill<<<(NE + 255) / 256, 256, 0, stream>>>(src, dst, row_start, cursor, csr_src);

    int nblk1 = (NN + 63) / 64;     // k_pass1: 64 rows/block
    int nblk  = (NN + 127) / 128;   // others: 128 rows/block
    // layer 0
    k_pass1<false><<<nblk1, 256, 0, stream>>>(x, nullptr, nullptr, nullptr, row_start, csr_src,
                                              epsp, 0, W1, b1, u, stats + 0);
    k_pass2<<<nblk, 256, 0, stream>>>(u, stats + 0, g1, be1, W2, b2, w0, stats + 128);
    // layer 1
    k_pass1<true><<<nblk1, 256, 0, stream>>>(w0, stats + 128, g2, be2, row_start, csr_src,
                                             epsp, 1, W1 + 4096, b1 + 64, u, stats + 256);
    k_pass2<<<nblk, 256, 0, stream>>>(u, stats + 256, g1 + 64, be1 + 64, W2 + 4096, b2 + 64, w1v, stats + 384);
    // layer 2
    k_pass1<true><<<nblk1, 256, 0, stream>>>(w1v, stats + 384, g2 + 64, be2 + 64, row_start, csr_src,
                                             epsp, 2, W1 + 8192, b1 + 128, u, stats + 512);
    k_pass2<<<nblk, 256, 0, stream>>>(u, stats + 512, g1 + 128, be1 + 128, W2 + 8192, b2 + 128, w2v, stats + 640);

    k_final<<<nblk, 256, 0, stream>>>(w0, w1v, w2v, stats, g2, be2, lin1W, lin1b, gateW, gateB, hh, gate);
    k_bounds<<<(NGR + 256) / 256, 256, 0, stream>>>(bidx, gstart);
    k_pool<<<NGR, 256, 0, stream>>>(hh, gate, gstart, pooled);
}